// Round 19
// baseline (48.456 us; speedup 1.0000x reference)
//
#include <hip/hip_runtime.h>
#include <hip/hip_fp16.h>

// CTC loss (blank=0, mean reduction, zero_infinity) for
// B=64, T=1024, K=512, L=100  ->  S = 2L+1 = 201 extended states.
//
// Ratio formulation: factor prod_t p_blank(t) out of all alpha states.
//   even states: a' = sums;  odd states: a' = sums * r  (r = p_lab/p_blank)
//
// Round-19: 3-stage overlap cascade (kernel-boundary sync only — R10/R16:
// fences/coop barriers are catastrophic; R17: chains are issue-bound).
//   K1: produce rows [0,192) u [832,1024); zero out[].
//   K2: blocks 0..63 chain chunks 0..11 (fwd rows 0..191 / bwd 1023..832,
//       reads only K1 rows) -> save state; blocks 64+: produce rows
//       [192,384) u [640,832) concurrently.
//   K3: restore, chain chunks 12..23 (fwd 192..383 / bwd 831..640, reads
//       K2 rows) -> save; blocks 64+: produce rows [384,640).
//   K4: restore, chain chunks 24..31 (fwd 384..511 / bwd 639..512), then
//       the verified log2-domain combine -> wave logsumexp -> atomicAdd.
// Producers now use DPP reduction ladders (row_shr+row_bcast, VALU pipe)
// instead of __shfl_xor (ds_bpermute, DS pipe) — R6-proven; 0-fill safe
// (max: m >= true max is shift-exact for softmax; sum: adds exact 0).
// Recursion math is byte-identical to the absmax-0.0 R15/R18 lineage:
// fp16 pair-packed pk[b][t/2][word][2], per-lane power-of-2 rescale every
// 8 steps (integer exponents, bit-built split factors), wave_shr:1 DPP.

#define TT 1024
#define BB 64
#define KK 512
#define LL 100

static constexpr float L2E = 1.44269504088896340736f;
static constexpr float LN2 = 0.69314718055994530942f;

// lane i <- lane i-1, lane 0 <- 0  (DPP wave_shr:1, VALU pipe)
__device__ __forceinline__ float dpp_shr1_z(float x) {
  return __builtin_bit_cast(float,
      __builtin_amdgcn_update_dpp(0, __builtin_bit_cast(int, x),
                                  0x138, 0xf, 0xf, true));
}
__device__ __forceinline__ int dpp_shr1_zi(int x) {
  return __builtin_amdgcn_update_dpp(0, x, 0x138, 0xf, 0xf, true);
}
__device__ __forceinline__ float slog2(float x) {
  return x > 0.0f ? log2f(x) : -1.0e30f;
}
__device__ __forceinline__ float2 upk(unsigned u) {
  return __half22float2(__builtin_bit_cast(__half2, u));
}

// wave64 max/sum via DPP (row_shr 1/2/4/8 + row_bcast15/31) + readlane(63).
// VALU-pipe only; 0-fill safe here (see header comment).
__device__ __forceinline__ float wave_max_dpp(float v) {
#define DPPMAX(C)                                                          \
  v = fmaxf(v, __builtin_bit_cast(float, __builtin_amdgcn_update_dpp(      \
                   0, __builtin_bit_cast(int, v), C, 0xf, 0xf, true)))
  DPPMAX(0x111); DPPMAX(0x112); DPPMAX(0x114); DPPMAX(0x118);
  DPPMAX(0x142); DPPMAX(0x143);
#undef DPPMAX
  return __builtin_bit_cast(float,
      __builtin_amdgcn_readlane(__builtin_bit_cast(int, v), 63));
}
__device__ __forceinline__ float wave_sum_dpp(float v) {
#define DPPADD(C)                                                          \
  v = v + __builtin_bit_cast(float, __builtin_amdgcn_update_dpp(           \
              0, __builtin_bit_cast(int, v), C, 0xf, 0xf, true))
  DPPADD(0x111); DPPADD(0x112); DPPADD(0x114); DPPADD(0x118);
  DPPADD(0x142); DPPADD(0x143);
#undef DPPADD
  return __builtin_bit_cast(float,
      __builtin_amdgcn_readlane(__builtin_bit_cast(int, v), 63));
}

// per-lane rescale: integer exponents, bit-constructed split factors
__device__ __forceinline__ void resc(float& S0, float& S1, float& S2,
                                     float& S3, int& ea, float& f1,
                                     float& f2) {
  const float m = fmaxf(fmaxf(S0, S1), fmaxf(S2, S3));
  int E = (int)((__float_as_uint(m) >> 23) & 255) - 127;
  E = (m > 0.0f) ? E : 0;
  const float sc = __uint_as_float((unsigned)(127 - E) << 23);
  S0 *= sc; S1 *= sc; S2 *= sc; S3 *= sc;
  ea += E;
  int dE = dpp_shr1_zi(ea) - ea;
  dE = dE < -250 ? -250 : (dE > 250 ? 250 : dE);
  const int h = dE / 2;
  f1 = __uint_as_float((unsigned)(127 + h) << 23);
  f2 = __uint_as_float((unsigned)(127 + (dE - h)) << 23);
}
__device__ __forceinline__ void refresh_f(int ea, float& f1, float& f2) {
  int dE = dpp_shr1_zi(ea) - ea;
  dE = dE < -250 ? -250 : (dE > 250 ? 250 : dE);
  const int h = dE / 2;
  f1 = __uint_as_float((unsigned)(127 + h) << 23);
  f2 = __uint_as_float((unsigned)(127 + (dE - h)) << 23);
}

__device__ __forceinline__ void fstep(float2 r, float mA, float mB,
                                      float& S0, float& S1, float& S2,
                                      float& S3, float f1, float f2) {
  const float A3 = dpp_shr1_z(S3) * f1 * f2;
  const float n0 = S0 + A3;
  const float n1 = (S0 + S1 + mA * A3) * r.x;
  const float n2 = S1 + S2;
  const float n3 = (S2 + S3 + mB * S1) * r.y;
  S0 = n0; S1 = n1; S2 = n2; S3 = n3;
}
__device__ __forceinline__ void bstep(float2 r, float mBb, float mAn,
                                      float& S0, float& S1, float& S2,
                                      float& S3, float f1, float f2) {
  const float s2 = dpp_shr1_z(r.x);             // label 2ii+2 ratio
  const float H0 = dpp_shr1_z(S0) * f1 * f2;
  const float H1 = dpp_shr1_z(S1) * f1 * f2;
  const float u = r.x * S1;
  const float v = r.y * S3;
  const float n0 = S0 + u;
  const float n1 = u + fmaf(mBb, v, S2);
  const float n2 = S2 + v;
  const float n3 = v + fmaf(mAn, s2 * H1, H0);
  S0 = n0; S1 = n1; S2 = n2; S3 = n3;
}

// chunk segment runners: CB = first chunk, NC = chunk count (16 steps ea,
// NC must be a multiple of 4)
template <int CB, int NC>
__device__ __forceinline__ void run_fwd(const unsigned* __restrict__ gb,
                                        float mA, float mB, float& S0,
                                        float& S1, float& S2, float& S3,
                                        int& ea, float& f1, float& f2) {
  uint2 RA[8], RB[8], RC[8], RD[8];
#define ISSUE(BUF, CHN)                                                    \
  do {                                                                     \
    if ((CHN) < NC) {                                                      \
      _Pragma("unroll") for (int j = 0; j < 8; ++j)                        \
        BUF[j] = *reinterpret_cast<const uint2*>(                          \
            gb + (size_t)((CB + (CHN)) * 8 + j) * 128);                    \
      __builtin_amdgcn_sched_barrier(0);                                   \
    }                                                                      \
  } while (0)
#define COMP(BUF)                                                          \
  do {                                                                     \
    _Pragma("unroll") for (int j = 0; j < 8; ++j) {                        \
      fstep(upk(BUF[j].x), mA, mB, S0, S1, S2, S3, f1, f2);                \
      fstep(upk(BUF[j].y), mA, mB, S0, S1, S2, S3, f1, f2);                \
      if ((j & 3) == 3) resc(S0, S1, S2, S3, ea, f1, f2);                  \
    }                                                                      \
  } while (0)
  ISSUE(RA, 0); ISSUE(RB, 1); ISSUE(RC, 2);
  for (int c = 0; c < NC; c += 4) {
    ISSUE(RD, c + 3); COMP(RA);
    ISSUE(RA, c + 4); COMP(RB);
    ISSUE(RB, c + 5); COMP(RC);
    ISSUE(RC, c + 6); COMP(RD);
  }
#undef ISSUE
#undef COMP
}

template <int CB, int NC>
__device__ __forceinline__ void run_bwd(const unsigned* __restrict__ gb,
                                        float mBb, float mAn, float& S0,
                                        float& S1, float& S2, float& S3,
                                        int& ea, float& f1, float& f2) {
  uint2 RA[8], RB[8], RC[8], RD[8];
#define ISSUE(BUF, CHN)                                                    \
  do {                                                                     \
    if ((CHN) < NC) {                                                      \
      _Pragma("unroll") for (int j = 0; j < 8; ++j)                        \
        BUF[j] = *reinterpret_cast<const uint2*>(                          \
            gb + (size_t)(511 - ((CB + (CHN)) * 8 + j)) * 128);            \
      __builtin_amdgcn_sched_barrier(0);                                   \
    }                                                                      \
  } while (0)
#define COMP(BUF)                                                          \
  do {                                                                     \
    _Pragma("unroll") for (int j = 0; j < 8; ++j) {                        \
      bstep(upk(BUF[j].y), mBb, mAn, S0, S1, S2, S3, f1, f2);              \
      bstep(upk(BUF[j].x), mBb, mAn, S0, S1, S2, S3, f1, f2);              \
      if ((j & 3) == 3) resc(S0, S1, S2, S3, ea, f1, f2);                  \
    }                                                                      \
  } while (0)
  ISSUE(RA, 0); ISSUE(RB, 1); ISSUE(RC, 2);
  for (int c = 0; c < NC; c += 4) {
    ISSUE(RD, c + 3); COMP(RA);
    ISSUE(RA, c + 4); COMP(RB);
    ISSUE(RB, c + 5); COMP(RC);
    ISSUE(RC, c + 6); COMP(RD);
  }
#undef ISSUE
#undef COMP
}

// one softmax row: 100 target ratios -> fp16x2 pair-packed pk + lb.
// Reductions via DPP ladders (VALU), not shfl_xor (DS pipe).
__device__ __forceinline__ void prob_row(const float* __restrict__ logits,
                                         const int* __restrict__ targets,
                                         unsigned* __restrict__ pk,
                                         float* __restrict__ lbArr,
                                         int b, int t, int lane, float* sp) {
  const int row = (b << 10) + t;
  const float* x = logits + (size_t)row * KK;
  const float4 v0 = reinterpret_cast<const float4*>(x)[lane];
  const float4 v1 = reinterpret_cast<const float4*>(x)[lane + 64];
  float4* sp4 = reinterpret_cast<float4*>(sp);
  sp4[lane] = v0;
  sp4[lane + 64] = v1;

  float m = fmaxf(fmaxf(fmaxf(v0.x, v0.y), fmaxf(v0.z, v0.w)),
                  fmaxf(fmaxf(v1.x, v1.y), fmaxf(v1.z, v1.w)));
  m = wave_max_dpp(m);                          // >= true max (0-fill safe)

  float e = exp2f((v0.x - m) * L2E) + exp2f((v0.y - m) * L2E) +
            exp2f((v0.z - m) * L2E) + exp2f((v0.w - m) * L2E) +
            exp2f((v1.x - m) * L2E) + exp2f((v1.y - m) * L2E) +
            exp2f((v1.z - m) * L2E) + exp2f((v1.w - m) * L2E);
  e = wave_sum_dpp(e);

  __syncthreads();
  const float xb = sp[0];                       // blank logit

  float ox = 0.0f, oy = 0.0f;
  if (lane >= 1 && lane <= 50) {
    const int2 c = *reinterpret_cast<const int2*>(
        targets + b * LL + (2 * lane - 2));
    ox = exp2f((sp[c.x] - xb) * L2E);           // ratio p_lab / p_blank
    oy = exp2f((sp[c.y] - xb) * L2E);
  }
  const int word = (lane == 0) ? 63 : (lane - 1);
  const __half2 h = __floats2half2_rn(ox, oy);
  pk[(size_t)(row >> 1) * 128 + word * 2 + (row & 1)] =
      __builtin_bit_cast(unsigned, h);
  if (lane == 0) lbArr[row] = (xb - m) * L2E + 9.0f - log2f(e);
}

// chain setup helpers
__device__ __forceinline__ void fwd_masks(const int* tg, int lane,
                                          float& mA, float& mB) {
  mA = 0.0f; mB = 0.0f;
  if (lane > 0 && 2 * lane <= LL - 1)
    mA = (tg[2 * lane] != tg[2 * lane - 1]) ? 1.0f : 0.0f;
  if (2 * lane + 1 <= LL - 1)
    mB = (tg[2 * lane + 1] != tg[2 * lane]) ? 1.0f : 0.0f;
}
__device__ __forceinline__ void bwd_masks(const int* tg, int lane,
                                          float& mBb, float& mAn, int& w) {
  const int ii = 50 - lane;
  w = (ii >= 0) ? ii : 50;                      // word 50 = zeros (pad)
  mBb = 0.0f; mAn = 0.0f;
  if (ii >= 0 && 2 * ii + 1 <= LL - 1)
    mBb = (tg[2 * ii + 1] != tg[2 * ii]) ? 1.0f : 0.0f;
  if (ii >= 0 && ii <= 48)
    mAn = (tg[2 * ii + 2] != tg[2 * ii + 1]) ? 1.0f : 0.0f;
}

// K1: rows [0,192) u [832,1024), all batches (384/batch); zero out[].
__global__ __launch_bounds__(256) void k_p1(
    const float* __restrict__ logits, const int* __restrict__ targets,
    unsigned* __restrict__ pk, float* __restrict__ lbArr,
    float* __restrict__ out) {
  if (blockIdx.x == 0 && threadIdx.x == 0) out[0] = 0.0f;
  const int wv = threadIdx.x >> 6;
  const int lane = threadIdx.x & 63;
  __shared__ float sx[4][KK];
  const int e = (blockIdx.x << 2) + wv;         // 0..24575
  const int b = e / 384;
  const int w = e - b * 384;
  const int t = (w < 192) ? w : (w + 640);      // [0,192) u [832,1024)
  prob_row(logits, targets, pk, lbArr, b, t, lane, sx[wv]);
}

// K2: blocks 0..63 chain chunks 0..11 (save st1); 64+: rows [192,384)u[640,832)
__global__ __launch_bounds__(256) void k_mid1(
    const float* __restrict__ logits, const int* __restrict__ targets,
    unsigned* __restrict__ pk, float* __restrict__ lbArr,
    float* __restrict__ st1) {
  const int lane = threadIdx.x & 63;
  const int wv = threadIdx.x >> 6;
  __shared__ float sx[4][KK];

  if (blockIdx.x >= BB) {
    const int e = ((blockIdx.x - BB) << 2) + wv; // 0..24575
    const int b = e / 384;
    const int w = e - b * 384;
    const int t = (w < 192) ? (w + 192) : (w + 448);  // [192,384)u[640,832)
    prob_row(logits, targets, pk, lbArr, b, t, lane, sx[wv]);
    return;
  }
  if (wv >= 2) return;
  const int b = blockIdx.x;
  const int dir = wv;
  const int* tg = targets + b * LL;

  float S0 = 0.0f, S1 = 0.0f, S2 = 0.0f, S3 = 0.0f;
  int ea = 0;
  float f1 = 1.0f, f2 = 1.0f;

  if (dir == 0) {
    const unsigned* gb = pk + (size_t)b * 512 * 128 + lane * 2;
    float mA, mB;
    fwd_masks(tg, lane, mA, mB);
    S0 = (lane == 0) ? 1.0f : 0.0f;             // virtual delta init
    run_fwd<0, 12>(gb, mA, mB, S0, S1, S2, S3, ea, f1, f2);
  } else {
    float mBb, mAn; int w;
    bwd_masks(tg, lane, mBb, mAn, w);
    const unsigned* gb = pk + (size_t)b * 512 * 128 + w * 2;
    if (lane == 0) S0 = 1.0f;                   // state 200 (ii = 50)
    if (lane == 1) S3 = 1.0f;                   // state 199 (ii = 49)
    run_bwd<0, 12>(gb, mBb, mAn, S0, S1, S2, S3, ea, f1, f2);
  }
  float* stp = st1 + (size_t)(b * 2 + dir) * 5 * 64;
  stp[0 * 64 + lane] = S0;
  stp[1 * 64 + lane] = S1;
  stp[2 * 64 + lane] = S2;
  stp[3 * 64 + lane] = S3;
  stp[4 * 64 + lane] = __int_as_float(ea);
}

// K3: blocks 0..63 chain chunks 12..23 (st1 -> st2); 64+: rows [384,640)
__global__ __launch_bounds__(256) void k_mid2(
    const float* __restrict__ logits, const int* __restrict__ targets,
    unsigned* __restrict__ pk, float* __restrict__ lbArr,
    const float* __restrict__ st1, float* __restrict__ st2) {
  const int lane = threadIdx.x & 63;
  const int wv = threadIdx.x >> 6;
  __shared__ float sx[4][KK];

  if (blockIdx.x >= BB) {
    const int e = ((blockIdx.x - BB) << 2) + wv; // 0..16383
    const int b = e >> 8;
    const int w = e & 255;
    prob_row(logits, targets, pk, lbArr, b, 384 + w, lane, sx[wv]);
    return;
  }
  if (wv >= 2) return;
  const int b = blockIdx.x;
  const int dir = wv;
  const int* tg = targets + b * LL;

  const float* sp = st1 + (size_t)(b * 2 + dir) * 5 * 64;
  float S0 = sp[0 * 64 + lane];
  float S1 = sp[1 * 64 + lane];
  float S2 = sp[2 * 64 + lane];
  float S3 = sp[3 * 64 + lane];
  int ea = __float_as_int(sp[4 * 64 + lane]);
  float f1, f2;
  refresh_f(ea, f1, f2);

  if (dir == 0) {
    const unsigned* gb = pk + (size_t)b * 512 * 128 + lane * 2;
    float mA, mB;
    fwd_masks(tg, lane, mA, mB);
    run_fwd<12, 12>(gb, mA, mB, S0, S1, S2, S3, ea, f1, f2);
  } else {
    float mBb, mAn; int w;
    bwd_masks(tg, lane, mBb, mAn, w);
    const unsigned* gb = pk + (size_t)b * 512 * 128 + w * 2;
    run_bwd<12, 12>(gb, mBb, mAn, S0, S1, S2, S3, ea, f1, f2);
  }
  float* stp = st2 + (size_t)(b * 2 + dir) * 5 * 64;
  stp[0 * 64 + lane] = S0;
  stp[1 * 64 + lane] = S1;
  stp[2 * 64 + lane] = S2;
  stp[3 * 64 + lane] = S3;
  stp[4 * 64 + lane] = __int_as_float(ea);
}

// K4: restore st2, chain chunks 24..31, combine (verified epilogue).
__global__ __launch_bounds__(128) void k_tail(
    const unsigned* __restrict__ pk, const float* __restrict__ lbArr,
    const int* __restrict__ targets, const float* __restrict__ st2,
    float* __restrict__ out) {
  const int lane = threadIdx.x & 63;
  const int wv = threadIdx.x >> 6;              // 0 = fwd, 1 = bwd
  const int b = blockIdx.x;
  const int dir = wv;
  const int* tg = targets + b * LL;

  __shared__ float sG[6][64];

  // early-issue lb partial loads (independent of the recursion)
  const float4* lbv = reinterpret_cast<const float4*>(lbArr + (size_t)b * TT);
  const int lbbase = (dir == 0) ? 0 : 128;
  const float4 lb0 = lbv[lbbase + lane];
  const float4 lb1 = lbv[lbbase + lane + 64];

  const float* sp = st2 + (size_t)(b * 2 + dir) * 5 * 64;
  float S0 = sp[0 * 64 + lane];
  float S1 = sp[1 * 64 + lane];
  float S2 = sp[2 * 64 + lane];
  float S3 = sp[3 * 64 + lane];
  int ea = __float_as_int(sp[4 * 64 + lane]);
  float f1, f2;
  refresh_f(ea, f1, f2);

  if (dir == 0) {
    const unsigned* gb = pk + (size_t)b * 512 * 128 + lane * 2;
    float mA, mB;
    fwd_masks(tg, lane, mA, mB);
    run_fwd<24, 8>(gb, mA, mB, S0, S1, S2, S3, ea, f1, f2);
  } else {
    float mBb, mAn; int w;
    bwd_masks(tg, lane, mBb, mAn, w);
    const unsigned* gb = pk + (size_t)b * 512 * 128 + w * 2;
    run_bwd<24, 8>(gb, mBb, mAn, S0, S1, S2, S3, ea, f1, f2);
  }

  // lb partial reduce
  float s4 = (lb0.x + lb0.y) + (lb0.z + lb0.w) +
             (lb1.x + lb1.y) + (lb1.z + lb1.w);
  #pragma unroll
  for (int d = 1; d < 64; d <<= 1) s4 += __shfl_xor(s4, d);

  if (dir == 1) {
    sG[0][lane] = S0; sG[1][lane] = S1; sG[2][lane] = S2; sG[3][lane] = S3;
    sG[4][lane] = (float)ea;
    if (lane == 0) sG[5][0] = s4;
  }
  __syncthreads();                              // backward publishes sG

  if (dir == 0) {
    const int gj = (lane <= 50) ? (50 - lane) : 63;
    const float eb = sG[4][gj];
    const float eff = (float)ea;
    float w0 = slog2(S0) + eff + slog2(sG[0][gj]) + eb;
    float w1 = slog2(S1) + eff + slog2(sG[1][gj]) + eb;
    float w2 = slog2(S2) + eff + slog2(sG[2][gj]) + eb;
    float w3 = slog2(S3) + eff + slog2(sG[3][gj]) + eb;
    float wm = fmaxf(fmaxf(w0, w1), fmaxf(w2, w3));
    #pragma unroll
    for (int d = 1; d < 64; d <<= 1) wm = fmaxf(wm, __shfl_xor(wm, d));
    float ss = exp2f(w0 - wm) + exp2f(w1 - wm) +
               exp2f(w2 - wm) + exp2f(w3 - wm);
    #pragma unroll
    for (int d = 1; d < 64; d <<= 1) ss += __shfl_xor(ss, d);

    if (lane == 0) {
      const float lbsum = s4 + sG[5][0];        // fwd + bwd halves
      float loss = 0.0f;                        // zero_infinity
      if (wm > -1.0e29f) {
        const float logl2 = wm + log2f(ss) + lbsum - (float)(TT * 9);
        loss = -(logl2 * LN2) / (float)LL;
      }
      atomicAdd(out, loss * (1.0f / (float)BB));
    }
  }
}

extern "C" void kernel_launch(void* const* d_in, const int* in_sizes, int n_in,
                              void* d_out, int out_size, void* d_ws, size_t ws_size,
                              hipStream_t stream) {
  const float* logits = (const float*)d_in[0];   // (64, 1024, 512) f32
  const int* targets = (const int*)d_in[1];      // (64, 100) i32
  float* out = (float*)d_out;                    // scalar f32

  unsigned* pk = (unsigned*)d_ws;                // 64*512*128 u32 (16 MB)
  float* lbArr = (float*)d_ws + (size_t)BB * 512 * 128;  // 64*1024 f32
  float* st1 = lbArr + (size_t)BB * TT;          // 64*2*5*64 f32
  float* st2 = st1 + (size_t)BB * 2 * 5 * 64;    // 64*2*5*64 f32

  hipLaunchKernelGGL(k_p1, dim3(BB * 384 / 4), dim3(256), 0, stream,
                     logits, targets, pk, lbArr, out);
  hipLaunchKernelGGL(k_mid1, dim3(BB + BB * 384 / 4), dim3(256), 0, stream,
                     logits, targets, pk, lbArr, st1);
  hipLaunchKernelGGL(k_mid2, dim3(BB + BB * 256 / 4), dim3(256), 0, stream,
                     logits, targets, pk, lbArr, st1, st2);
  hipLaunchKernelGGL(k_tail, dim3(BB), dim3(128), 0, stream,
                     pk, lbArr, targets, st2, out);
}

// Round 20
// 47.802 us; speedup vs baseline: 1.0137x; 1.0137x over previous
//
#include <hip/hip_runtime.h>
#include <hip/hip_fp16.h>

// CTC loss (blank=0, mean reduction, zero_infinity) for
// B=64, T=1024, K=512, L=100  ->  S = 2L+1 = 201 extended states.
//
// Ratio formulation: factor prod_t p_blank(t) out of all alpha states.
//   even states: a' = sums;  odd states: a' = sums * r  (r = p_lab/p_blank)
//
// Round-20: consolidation on the R18 2-stage overlap (R19: 3 stages lose
// to launch-gap costs).  Kernel-boundary sync only (R10/R16: fences/coop
// barriers catastrophic; R17: chains are issue-bound, 1 chain wave/SIMD).
//   K1 k_probs_edge: produce rows [0,320) u [704,1024); zero out[].
//   K2 k_mid: blocks 0..63 chain chunks 0..19 (fwd rows 0..319 / bwd
//     1023..704, reads only K1 rows) -> save state; blocks 64+: produce
//     rows [320,704) concurrently.
//   K3 k_tail: restore, chain chunks 20..31, verified log2-domain
//     combine -> wave logsumexp -> atomicAdd(out, loss/64).
// Producer changes this round: (a) NO __syncthreads in prob_row — the
// LDS slice is per-wave scratch; same-wave ds_write->ds_read is ordered
// by the in-order DS queue; the barrier only coupled 4 independent waves.
// (b) blank logit via readlane(v0.x, 0) instead of LDS. (c) DPP
// reduction ladders (VALU pipe; R19-verified, 0-fill safe).
// Recursion math byte-identical to the absmax-0.0 R15/R18 lineage.

#define TT 1024
#define BB 64
#define KK 512
#define LL 100

static constexpr float L2E = 1.44269504088896340736f;
static constexpr float LN2 = 0.69314718055994530942f;

// lane i <- lane i-1, lane 0 <- 0  (DPP wave_shr:1, VALU pipe)
__device__ __forceinline__ float dpp_shr1_z(float x) {
  return __builtin_bit_cast(float,
      __builtin_amdgcn_update_dpp(0, __builtin_bit_cast(int, x),
                                  0x138, 0xf, 0xf, true));
}
__device__ __forceinline__ int dpp_shr1_zi(int x) {
  return __builtin_amdgcn_update_dpp(0, x, 0x138, 0xf, 0xf, true);
}
__device__ __forceinline__ float slog2(float x) {
  return x > 0.0f ? log2f(x) : -1.0e30f;
}
__device__ __forceinline__ float2 upk(unsigned u) {
  return __half22float2(__builtin_bit_cast(__half2, u));
}

// wave64 max/sum via DPP (row_shr 1/2/4/8 + row_bcast15/31) + readlane(63).
// VALU-pipe only; 0-fill safe (max: m >= true max is shift-exact for
// softmax; sum: adds exact zeros).
__device__ __forceinline__ float wave_max_dpp(float v) {
#define DPPMAX(C)                                                          \
  v = fmaxf(v, __builtin_bit_cast(float, __builtin_amdgcn_update_dpp(      \
                   0, __builtin_bit_cast(int, v), C, 0xf, 0xf, true)))
  DPPMAX(0x111); DPPMAX(0x112); DPPMAX(0x114); DPPMAX(0x118);
  DPPMAX(0x142); DPPMAX(0x143);
#undef DPPMAX
  return __builtin_bit_cast(float,
      __builtin_amdgcn_readlane(__builtin_bit_cast(int, v), 63));
}
__device__ __forceinline__ float wave_sum_dpp(float v) {
#define DPPADD(C)                                                          \
  v = v + __builtin_bit_cast(float, __builtin_amdgcn_update_dpp(           \
              0, __builtin_bit_cast(int, v), C, 0xf, 0xf, true))
  DPPADD(0x111); DPPADD(0x112); DPPADD(0x114); DPPADD(0x118);
  DPPADD(0x142); DPPADD(0x143);
#undef DPPADD
  return __builtin_bit_cast(float,
      __builtin_amdgcn_readlane(__builtin_bit_cast(int, v), 63));
}

// per-lane rescale: integer exponents, bit-constructed split factors
__device__ __forceinline__ void resc(float& S0, float& S1, float& S2,
                                     float& S3, int& ea, float& f1,
                                     float& f2) {
  const float m = fmaxf(fmaxf(S0, S1), fmaxf(S2, S3));
  int E = (int)((__float_as_uint(m) >> 23) & 255) - 127;
  E = (m > 0.0f) ? E : 0;
  const float sc = __uint_as_float((unsigned)(127 - E) << 23);
  S0 *= sc; S1 *= sc; S2 *= sc; S3 *= sc;
  ea += E;
  int dE = dpp_shr1_zi(ea) - ea;
  dE = dE < -250 ? -250 : (dE > 250 ? 250 : dE);
  const int h = dE / 2;
  f1 = __uint_as_float((unsigned)(127 + h) << 23);
  f2 = __uint_as_float((unsigned)(127 + (dE - h)) << 23);
}
__device__ __forceinline__ void refresh_f(int ea, float& f1, float& f2) {
  int dE = dpp_shr1_zi(ea) - ea;
  dE = dE < -250 ? -250 : (dE > 250 ? 250 : dE);
  const int h = dE / 2;
  f1 = __uint_as_float((unsigned)(127 + h) << 23);
  f2 = __uint_as_float((unsigned)(127 + (dE - h)) << 23);
}

__device__ __forceinline__ void fstep(float2 r, float mA, float mB,
                                      float& S0, float& S1, float& S2,
                                      float& S3, float f1, float f2) {
  const float A3 = dpp_shr1_z(S3) * f1 * f2;
  const float n0 = S0 + A3;
  const float n1 = (S0 + S1 + mA * A3) * r.x;
  const float n2 = S1 + S2;
  const float n3 = (S2 + S3 + mB * S1) * r.y;
  S0 = n0; S1 = n1; S2 = n2; S3 = n3;
}
__device__ __forceinline__ void bstep(float2 r, float mBb, float mAn,
                                      float& S0, float& S1, float& S2,
                                      float& S3, float f1, float f2) {
  const float s2 = dpp_shr1_z(r.x);             // label 2ii+2 ratio
  const float H0 = dpp_shr1_z(S0) * f1 * f2;
  const float H1 = dpp_shr1_z(S1) * f1 * f2;
  const float u = r.x * S1;
  const float v = r.y * S3;
  const float n0 = S0 + u;
  const float n1 = u + fmaf(mBb, v, S2);
  const float n2 = S2 + v;
  const float n3 = v + fmaf(mAn, s2 * H1, H0);
  S0 = n0; S1 = n1; S2 = n2; S3 = n3;
}

// chunk segment runners: CB = first chunk, NC = chunk count (16 steps ea,
// NC must be a multiple of 4)
template <int CB, int NC>
__device__ __forceinline__ void run_fwd(const unsigned* __restrict__ gb,
                                        float mA, float mB, float& S0,
                                        float& S1, float& S2, float& S3,
                                        int& ea, float& f1, float& f2) {
  uint2 RA[8], RB[8], RC[8], RD[8];
#define ISSUE(BUF, CHN)                                                    \
  do {                                                                     \
    if ((CHN) < NC) {                                                      \
      _Pragma("unroll") for (int j = 0; j < 8; ++j)                        \
        BUF[j] = *reinterpret_cast<const uint2*>(                          \
            gb + (size_t)((CB + (CHN)) * 8 + j) * 128);                    \
      __builtin_amdgcn_sched_barrier(0);                                   \
    }                                                                      \
  } while (0)
#define COMP(BUF)                                                          \
  do {                                                                     \
    _Pragma("unroll") for (int j = 0; j < 8; ++j) {                        \
      fstep(upk(BUF[j].x), mA, mB, S0, S1, S2, S3, f1, f2);                \
      fstep(upk(BUF[j].y), mA, mB, S0, S1, S2, S3, f1, f2);                \
      if ((j & 3) == 3) resc(S0, S1, S2, S3, ea, f1, f2);                  \
    }                                                                      \
  } while (0)
  ISSUE(RA, 0); ISSUE(RB, 1); ISSUE(RC, 2);
  for (int c = 0; c < NC; c += 4) {
    ISSUE(RD, c + 3); COMP(RA);
    ISSUE(RA, c + 4); COMP(RB);
    ISSUE(RB, c + 5); COMP(RC);
    ISSUE(RC, c + 6); COMP(RD);
  }
#undef ISSUE
#undef COMP
}

template <int CB, int NC>
__device__ __forceinline__ void run_bwd(const unsigned* __restrict__ gb,
                                        float mBb, float mAn, float& S0,
                                        float& S1, float& S2, float& S3,
                                        int& ea, float& f1, float& f2) {
  uint2 RA[8], RB[8], RC[8], RD[8];
#define ISSUE(BUF, CHN)                                                    \
  do {                                                                     \
    if ((CHN) < NC) {                                                      \
      _Pragma("unroll") for (int j = 0; j < 8; ++j)                        \
        BUF[j] = *reinterpret_cast<const uint2*>(                          \
            gb + (size_t)(511 - ((CB + (CHN)) * 8 + j)) * 128);            \
      __builtin_amdgcn_sched_barrier(0);                                   \
    }                                                                      \
  } while (0)
#define COMP(BUF)                                                          \
  do {                                                                     \
    _Pragma("unroll") for (int j = 0; j < 8; ++j) {                        \
      bstep(upk(BUF[j].y), mBb, mAn, S0, S1, S2, S3, f1, f2);              \
      bstep(upk(BUF[j].x), mBb, mAn, S0, S1, S2, S3, f1, f2);              \
      if ((j & 3) == 3) resc(S0, S1, S2, S3, ea, f1, f2);                  \
    }                                                                      \
  } while (0)
  ISSUE(RA, 0); ISSUE(RB, 1); ISSUE(RC, 2);
  for (int c = 0; c < NC; c += 4) {
    ISSUE(RD, c + 3); COMP(RA);
    ISSUE(RA, c + 4); COMP(RB);
    ISSUE(RB, c + 5); COMP(RC);
    ISSUE(RC, c + 6); COMP(RD);
  }
#undef ISSUE
#undef COMP
}

// one softmax row: 100 target ratios -> fp16x2 pair-packed pk + lb.
// NO barrier: sp is per-wave LDS scratch; same-wave ds_write->ds_read is
// ordered by the in-order DS queue. Reductions via DPP ladders (VALU).
__device__ __forceinline__ void prob_row(const float* __restrict__ logits,
                                         const int* __restrict__ targets,
                                         unsigned* __restrict__ pk,
                                         float* __restrict__ lbArr,
                                         int b, int t, int lane, float* sp) {
  const int row = (b << 10) + t;
  const float* x = logits + (size_t)row * KK;
  const float4 v0 = reinterpret_cast<const float4*>(x)[lane];
  const float4 v1 = reinterpret_cast<const float4*>(x)[lane + 64];
  float4* sp4 = reinterpret_cast<float4*>(sp);
  sp4[lane] = v0;
  sp4[lane + 64] = v1;

  float m = fmaxf(fmaxf(fmaxf(v0.x, v0.y), fmaxf(v0.z, v0.w)),
                  fmaxf(fmaxf(v1.x, v1.y), fmaxf(v1.z, v1.w)));
  m = wave_max_dpp(m);                          // >= true max (0-fill safe)

  float e = exp2f((v0.x - m) * L2E) + exp2f((v0.y - m) * L2E) +
            exp2f((v0.z - m) * L2E) + exp2f((v0.w - m) * L2E) +
            exp2f((v1.x - m) * L2E) + exp2f((v1.y - m) * L2E) +
            exp2f((v1.z - m) * L2E) + exp2f((v1.w - m) * L2E);
  e = wave_sum_dpp(e);

  // blank logit = lane 0's v0.x (no LDS dependency)
  const float xb = __builtin_bit_cast(float,
      __builtin_amdgcn_readlane(__builtin_bit_cast(int, v0.x), 0));

  float ox = 0.0f, oy = 0.0f;
  if (lane >= 1 && lane <= 50) {
    const int2 c = *reinterpret_cast<const int2*>(
        targets + b * LL + (2 * lane - 2));
    ox = exp2f((sp[c.x] - xb) * L2E);           // ratio p_lab / p_blank
    oy = exp2f((sp[c.y] - xb) * L2E);
  }
  const int word = (lane == 0) ? 63 : (lane - 1);
  const __half2 h = __floats2half2_rn(ox, oy);
  pk[(size_t)(row >> 1) * 128 + word * 2 + (row & 1)] =
      __builtin_bit_cast(unsigned, h);
  if (lane == 0) lbArr[row] = (xb - m) * L2E + 9.0f - log2f(e);
}

// chain setup helpers
__device__ __forceinline__ void fwd_masks(const int* tg, int lane,
                                          float& mA, float& mB) {
  mA = 0.0f; mB = 0.0f;
  if (lane > 0 && 2 * lane <= LL - 1)
    mA = (tg[2 * lane] != tg[2 * lane - 1]) ? 1.0f : 0.0f;
  if (2 * lane + 1 <= LL - 1)
    mB = (tg[2 * lane + 1] != tg[2 * lane]) ? 1.0f : 0.0f;
}
__device__ __forceinline__ void bwd_masks(const int* tg, int lane,
                                          float& mBb, float& mAn, int& w) {
  const int ii = 50 - lane;
  w = (ii >= 0) ? ii : 50;                      // word 50 = zeros (pad)
  mBb = 0.0f; mAn = 0.0f;
  if (ii >= 0 && 2 * ii + 1 <= LL - 1)
    mBb = (tg[2 * ii + 1] != tg[2 * ii]) ? 1.0f : 0.0f;
  if (ii >= 0 && ii <= 48)
    mAn = (tg[2 * ii + 2] != tg[2 * ii + 1]) ? 1.0f : 0.0f;
}

// K1: edge rows [0,320) u [704,1024), all batches (640/batch); zero out[].
__global__ __launch_bounds__(256) void k_probs_edge(
    const float* __restrict__ logits, const int* __restrict__ targets,
    unsigned* __restrict__ pk, float* __restrict__ lbArr,
    float* __restrict__ out) {
  if (blockIdx.x == 0 && threadIdx.x == 0) out[0] = 0.0f;
  const int wv = threadIdx.x >> 6;
  const int lane = threadIdx.x & 63;
  __shared__ float sx[4][KK];
  const int e = (blockIdx.x << 2) + wv;         // 0..40959
  const int b = e / 640;
  const int w = e - b * 640;
  const int t = (w < 320) ? w : (w + 384);      // [0,320) u [704,1024)
  prob_row(logits, targets, pk, lbArr, b, t, lane, sx[wv]);
}

// K2: blocks 0..63 chain chunks 0..19 (save st); 64+: rows [320,704)
__global__ __launch_bounds__(256) void k_mid(
    const float* __restrict__ logits, const int* __restrict__ targets,
    unsigned* __restrict__ pk, float* __restrict__ lbArr,
    float* __restrict__ st) {
  const int lane = threadIdx.x & 63;
  const int wv = threadIdx.x >> 6;
  __shared__ float sx[4][KK];

  if (blockIdx.x >= BB) {
    const int e = ((blockIdx.x - BB) << 2) + wv; // 0..24575
    const int b = e / 384;
    const int w = e - b * 384;
    prob_row(logits, targets, pk, lbArr, b, 320 + w, lane, sx[wv]);
    return;
  }
  if (wv >= 2) return;                          // chain blocks: 2 waves
  const int b = blockIdx.x;
  const int dir = wv;                           // 0 = fwd, 1 = bwd
  const int* tg = targets + b * LL;

  float S0 = 0.0f, S1 = 0.0f, S2 = 0.0f, S3 = 0.0f;
  int ea = 0;
  float f1 = 1.0f, f2 = 1.0f;

  if (dir == 0) {
    const unsigned* gb = pk + (size_t)b * 512 * 128 + lane * 2;
    float mA, mB;
    fwd_masks(tg, lane, mA, mB);
    S0 = (lane == 0) ? 1.0f : 0.0f;             // virtual delta init
    run_fwd<0, 20>(gb, mA, mB, S0, S1, S2, S3, ea, f1, f2);
  } else {
    float mBb, mAn; int w;
    bwd_masks(tg, lane, mBb, mAn, w);
    const unsigned* gb = pk + (size_t)b * 512 * 128 + w * 2;
    if (lane == 0) S0 = 1.0f;                   // state 200 (ii = 50)
    if (lane == 1) S3 = 1.0f;                   // state 199 (ii = 49)
    run_bwd<0, 20>(gb, mBb, mAn, S0, S1, S2, S3, ea, f1, f2);
  }
  float* stp = st + (size_t)(b * 2 + dir) * 5 * 64;
  stp[0 * 64 + lane] = S0;
  stp[1 * 64 + lane] = S1;
  stp[2 * 64 + lane] = S2;
  stp[3 * 64 + lane] = S3;
  stp[4 * 64 + lane] = __int_as_float(ea);
}

// K3: restore, chain chunks 20..31, combine (verified epilogue).
__global__ __launch_bounds__(128) void k_tail(
    const unsigned* __restrict__ pk, const float* __restrict__ lbArr,
    const int* __restrict__ targets, const float* __restrict__ st,
    float* __restrict__ out) {
  const int lane = threadIdx.x & 63;
  const int wv = threadIdx.x >> 6;              // 0 = fwd, 1 = bwd
  const int b = blockIdx.x;
  const int dir = wv;
  const int* tg = targets + b * LL;

  __shared__ float sG[6][64];

  // early-issue lb partial loads (independent of the recursion)
  const float4* lbv = reinterpret_cast<const float4*>(lbArr + (size_t)b * TT);
  const int lbbase = (dir == 0) ? 0 : 128;
  const float4 lb0 = lbv[lbbase + lane];
  const float4 lb1 = lbv[lbbase + lane + 64];

  const float* sp = st + (size_t)(b * 2 + dir) * 5 * 64;
  float S0 = sp[0 * 64 + lane];
  float S1 = sp[1 * 64 + lane];
  float S2 = sp[2 * 64 + lane];
  float S3 = sp[3 * 64 + lane];
  int ea = __float_as_int(sp[4 * 64 + lane]);
  float f1, f2;
  refresh_f(ea, f1, f2);                        // same values K2 ended with

  if (dir == 0) {
    const unsigned* gb = pk + (size_t)b * 512 * 128 + lane * 2;
    float mA, mB;
    fwd_masks(tg, lane, mA, mB);
    run_fwd<20, 12>(gb, mA, mB, S0, S1, S2, S3, ea, f1, f2);
  } else {
    float mBb, mAn; int w;
    bwd_masks(tg, lane, mBb, mAn, w);
    const unsigned* gb = pk + (size_t)b * 512 * 128 + w * 2;
    run_bwd<20, 12>(gb, mBb, mAn, S0, S1, S2, S3, ea, f1, f2);
  }

  // lb partial reduce
  float s4 = (lb0.x + lb0.y) + (lb0.z + lb0.w) +
             (lb1.x + lb1.y) + (lb1.z + lb1.w);
  #pragma unroll
  for (int d = 1; d < 64; d <<= 1) s4 += __shfl_xor(s4, d);

  if (dir == 1) {
    sG[0][lane] = S0; sG[1][lane] = S1; sG[2][lane] = S2; sG[3][lane] = S3;
    sG[4][lane] = (float)ea;
    if (lane == 0) sG[5][0] = s4;
  }
  __syncthreads();                              // backward publishes sG

  if (dir == 0) {
    const int gj = (lane <= 50) ? (50 - lane) : 63;
    const float eb = sG[4][gj];
    const float eff = (float)ea;
    float w0 = slog2(S0) + eff + slog2(sG[0][gj]) + eb;
    float w1 = slog2(S1) + eff + slog2(sG[1][gj]) + eb;
    float w2 = slog2(S2) + eff + slog2(sG[2][gj]) + eb;
    float w3 = slog2(S3) + eff + slog2(sG[3][gj]) + eb;
    float wm = fmaxf(fmaxf(w0, w1), fmaxf(w2, w3));
    #pragma unroll
    for (int d = 1; d < 64; d <<= 1) wm = fmaxf(wm, __shfl_xor(wm, d));
    float ss = exp2f(w0 - wm) + exp2f(w1 - wm) +
               exp2f(w2 - wm) + exp2f(w3 - wm);
    #pragma unroll
    for (int d = 1; d < 64; d <<= 1) ss += __shfl_xor(ss, d);

    if (lane == 0) {
      const float lbsum = s4 + sG[5][0];        // fwd + bwd halves
      float loss = 0.0f;                        // zero_infinity
      if (wm > -1.0e29f) {
        const float logl2 = wm + log2f(ss) + lbsum - (float)(TT * 9);
        loss = -(logl2 * LN2) / (float)LL;
      }
      atomicAdd(out, loss * (1.0f / (float)BB));
    }
  }
}

extern "C" void kernel_launch(void* const* d_in, const int* in_sizes, int n_in,
                              void* d_out, int out_size, void* d_ws, size_t ws_size,
                              hipStream_t stream) {
  const float* logits = (const float*)d_in[0];   // (64, 1024, 512) f32
  const int* targets = (const int*)d_in[1];      // (64, 100) i32
  float* out = (float*)d_out;                    // scalar f32

  unsigned* pk = (unsigned*)d_ws;                // 64*512*128 u32 (16 MB)
  float* lbArr = (float*)d_ws + (size_t)BB * 512 * 128;  // 64*1024 f32
  float* st = lbArr + (size_t)BB * TT;           // 64*2*5*64 f32

  hipLaunchKernelGGL(k_probs_edge, dim3(BB * 640 / 4), dim3(256), 0, stream,
                     logits, targets, pk, lbArr, out);
  hipLaunchKernelGGL(k_mid, dim3(BB + BB * 384 / 4), dim3(256), 0, stream,
                     logits, targets, pk, lbArr, st);
  hipLaunchKernelGGL(k_tail, dim3(BB), dim3(128), 0, stream,
                     pk, lbArr, targets, st, out);
}